// Round 5
// baseline (493.015 us; speedup 1.0000x reference)
//
#include <hip/hip_runtime.h>
#include <cstddef>
#include <cstdint>

constexpr int NN = 50000;          // nodes
constexpr int NE = 800000;         // edges (no self loops)
constexpr int ET = NE + NN;        // edges + self loops
constexpr int NB = 50;             // graphs
constexpr int SCAN_B = 1024;
constexpr int NBLK = (NN + SCAN_B - 1) / SCAN_B;   // 49
constexpr int NPB_F = 16;                          // nodes/block, front node branch
constexpr int NPB_T = 8;                           // nodes/block, transform (R12-proven)
constexpr int NTB_F = NN / NPB_F;                  // front node blocks (3125)
constexpr int NTB_T = NN / NPB_T;                  // nt64 blocks (6250)
constexpr int MLPB = (ET + 1023) / 1024;           // edge-mlp blocks (4 edges/thread)

typedef float v2f __attribute__((ext_vector_type(2)));

__device__ __forceinline__ float eluf(float x) { return x > 0.f ? x : expm1f(x); }

// round-to-nearest-even fp32 -> bf16 (as ushort)
__device__ __forceinline__ unsigned short f2bf(float f) {
    unsigned int u = __float_as_uint(f);
    unsigned int r = (u + 0x7fffu + ((u >> 16) & 1u)) >> 16;
    return (unsigned short)r;
}

// Interleaved 4-node {vs,vd} reduction over 64 lanes (R14-proven).
template <int NPB>
__device__ __forceinline__ void alpha_reduce_store(const float* acc, float as_t, float ad_t,
                                                   int lane, int head, int n0,
                                                   float* __restrict__ asrc,
                                                   float* __restrict__ adst) {
    #pragma unroll
    for (int g = 0; g < NPB; g += 4) {
        float x0, x1, x2, x3;
        {
            float vs, vd;
            vs = acc[g + 0] * as_t; vd = acc[g + 0] * ad_t;
            x0 = ((lane & 1) ? vd : vs) + __shfl_xor((lane & 1) ? vs : vd, 1);
            vs = acc[g + 1] * as_t; vd = acc[g + 1] * ad_t;
            x1 = ((lane & 1) ? vd : vs) + __shfl_xor((lane & 1) ? vs : vd, 1);
            vs = acc[g + 2] * as_t; vd = acc[g + 2] * ad_t;
            x2 = ((lane & 1) ? vd : vs) + __shfl_xor((lane & 1) ? vs : vd, 1);
            vs = acc[g + 3] * as_t; vd = acc[g + 3] * ad_t;
            x3 = ((lane & 1) ? vd : vs) + __shfl_xor((lane & 1) ? vs : vd, 1);
        }
        float y0 = ((lane & 2) ? x1 : x0) + __shfl_xor((lane & 2) ? x0 : x1, 2);
        float y1 = ((lane & 2) ? x3 : x2) + __shfl_xor((lane & 2) ? x2 : x3, 2);
        float z  = ((lane & 4) ? y1 : y0) + __shfl_xor((lane & 4) ? y0 : y1, 4);
        z += __shfl_xor(z, 8);
        z += __shfl_xor(z, 16);
        z += __shfl_xor(z, 32);
        if (lane < 8) {
            int node = n0 + g + (lane >> 1);
            if (lane & 1) adst[node * 4 + head] = z;
            else          asrc[node * 4 + head] = z;
        }
    }
}

// ---------------- per-node aggregation body (R9 2-deep two-half structure) ----------------
// WRITE_LDS: also deposit the elu'd output row into xs_row (for fused transform).
template <bool WRITE_LDS>
__device__ __forceinline__ void aggregate_one_node(
        int widx, int lane,
        const unsigned short* __restrict__ hb,
        const float* __restrict__ asrc, const float* __restrict__ adst,
        const int2* __restrict__ csr, const float* __restrict__ ce_l,
        const float* __restrict__ bias_l, const int* __restrict__ row_ptr,
        float* __restrict__ xi, int residual, float* xs_row) {
    int half = lane >> 5;
    int li = lane & 31;        // channels li*8 .. li*8+7
    int head = li >> 3;        // head
    int start = row_ptr[widx], end = row_ptr[widx + 1];
    float adw = adst[widx * 4 + head];
    float ceh = ce_l[head];
    const uint4* hbv = (const uint4*)hb;

    v2f acc2[4];
    #pragma unroll
    for (int r = 0; r < 4; ++r) { acc2[r].x = 0.f; acc2[r].y = 0.f; }
    float psum = 0.f;

    #define PROC(EI)                                                                  \
        {                                                                             \
            const int2 se = csr[EI];                                                  \
            int s = se.x;                                                             \
            float w = __int_as_float(se.y);                                           \
            const uint4 q = hbv[(unsigned)s * 32u + (unsigned)li];                    \
            float v = asrc[s * 4 + head] + adw + w * ceh;                             \
            v = v > 0.f ? v : 0.2f * v;                                               \
            float p = __expf(v);                                                      \
            psum += p;                                                                \
            v2f pv; pv.x = p; pv.y = p;                                               \
            v2f h0; h0.x = __uint_as_float(q.x << 16); h0.y = __uint_as_float(q.x & 0xffff0000u); \
            v2f h1; h1.x = __uint_as_float(q.y << 16); h1.y = __uint_as_float(q.y & 0xffff0000u); \
            v2f h2; h2.x = __uint_as_float(q.z << 16); h2.y = __uint_as_float(q.z & 0xffff0000u); \
            v2f h3; h3.x = __uint_as_float(q.w << 16); h3.y = __uint_as_float(q.w & 0xffff0000u); \
            acc2[0] += pv * h0;                                                       \
            acc2[1] += pv * h1;                                                       \
            acc2[2] += pv * h2;                                                       \
            acc2[3] += pv * h3;                                                       \
        }

    int ei = start + half;
    for (; ei + 2 < end; ei += 4) {   // 2 edges per half per iter -> 2 gathers in flight
        PROC(ei);
        PROC(ei + 2);
    }
    if (ei < end) PROC(ei);
    #undef PROC

    float acc[8];
    acc[0] = acc2[0].x; acc[1] = acc2[0].y; acc[2] = acc2[1].x; acc[3] = acc2[1].y;
    acc[4] = acc2[2].x; acc[5] = acc2[2].y; acc[6] = acc2[3].x; acc[7] = acc2[3].y;

    // combine the two halves (same channels, disjoint edge sets)
    psum += __shfl_xor(psum, 32);
    #pragma unroll
    for (int r = 0; r < 8; ++r) acc[r] += __shfl_xor(acc[r], 32);

    float inv = 1.f / (psum + 1e-16f);
    #pragma unroll
    for (int r = 0; r < 8; ++r) acc[r] *= inv;

    // head mean: lanes li, li^8, li^16, li^24 hold same channel-in-head, different heads
    #pragma unroll
    for (int r = 0; r < 8; ++r) {
        acc[r] += __shfl_xor(acc[r], 8);
        acc[r] += __shfl_xor(acc[r], 16);
        acc[r] *= 0.25f;
    }

    if (lane < 8) {
        int c0 = lane * 8;
        const float4 b0 = *(const float4*)(bias_l + c0);
        const float4 b1 = *(const float4*)(bias_l + c0 + 4);
        float4 v0, v1;
        v0.x = acc[0] + b0.x; v0.y = acc[1] + b0.y; v0.z = acc[2] + b0.z; v0.w = acc[3] + b0.w;
        v1.x = acc[4] + b1.x; v1.y = acc[5] + b1.y; v1.z = acc[6] + b1.z; v1.w = acc[7] + b1.w;
        float* xo = xi + (size_t)widx * 64 + c0;
        if (residual) {
            const float4 p0 = *(const float4*)xo;
            const float4 p1 = *(const float4*)(xo + 4);
            v0.x += p0.x; v0.y += p0.y; v0.z += p0.z; v0.w += p0.w;
            v1.x += p1.x; v1.y += p1.y; v1.z += p1.z; v1.w += p1.w;
        }
        v0.x = eluf(v0.x); v0.y = eluf(v0.y); v0.z = eluf(v0.z); v0.w = eluf(v0.w);
        v1.x = eluf(v1.x); v1.y = eluf(v1.y); v1.z = eluf(v1.z); v1.w = eluf(v1.w);
        *(float4*)xo = v0;
        *(float4*)(xo + 4) = v1;
        if (WRITE_LDS) {
            *(float4*)(xs_row + c0) = v0;
            *(float4*)(xs_row + c0 + 4) = v1;
        }
    }
}

// ---------------- front kernel: edge-MLP blocks FIRST (long-latency work starts
// early; node blocks fill behind), then node_transform<16>. R17.
__global__ void front_kernel(const float* __restrict__ xin, const float* __restrict__ W,
                             const float* __restrict__ a_s, const float* __restrict__ a_d,
                             unsigned short* __restrict__ hb, float* __restrict__ asrc,
                             float* __restrict__ adst,
                             const float* __restrict__ ea,
                             const float* __restrict__ w1, const float* __restrict__ b1,
                             const float* __restrict__ w2, const float* __restrict__ b2,
                             const int* __restrict__ ei_dst, int* __restrict__ deg,
                             int2* __restrict__ ewp, float* __restrict__ ew_sum) {
    __shared__ float wt[64 * 8];
    __shared__ float wsum[4];
    __shared__ unsigned short hs[NPB_F * 256];
    const int t = threadIdx.x;
    if (blockIdx.x >= MLPB) {
        // ----- node_transform, FIN=16, scalar/uniform x loads (R12-proven) -----
        const int FIN = 16;
        const int n0 = (blockIdx.x - MLPB) * NPB_F;
        float acc[NPB_F];
        #pragma unroll
        for (int i = 0; i < NPB_F; ++i) acc[i] = 0.f;
        #pragma unroll 4
        for (int k = 0; k < FIN; ++k) {
            float wv = W[k * 256 + t];
            #pragma unroll
            for (int i = 0; i < NPB_F; ++i)
                acc[i] += xin[(size_t)(n0 + i) * FIN + k] * wv;   // uniform address
        }
        int lane = t & 63, head = t >> 6;
        #pragma unroll
        for (int i = 0; i < NPB_F; ++i) hs[i * 256 + t] = f2bf(acc[i]);
        alpha_reduce_store<NPB_F>(acc, a_s[t], a_d[t], lane, head, n0, asrc, adst);
        __syncthreads();
        ((uint4*)(hb + (size_t)n0 * 256))[t]       = ((const uint4*)hs)[t];
        ((uint4*)(hb + (size_t)n0 * 256))[t + 256] = ((const uint4*)hs)[t + 256];
    } else {
        // ----- edge-MLP + histogram, 4 edges/thread -----
        if (t < 64) {
            #pragma unroll
            for (int i = 0; i < 5; ++i) wt[t * 8 + i] = w1[i * 64 + t];
            wt[t * 8 + 5] = b1[t];
            wt[t * 8 + 6] = w2[t];
            wt[t * 8 + 7] = 0.f;
        }
        __syncthreads();
        const int e0 = blockIdx.x * 1024 + t;
        float a0[4], a1[4], a2[4], a3[4], a4[4], acc[4];
        #pragma unroll
        for (int m = 0; m < 4; ++m) {
            int e = e0 + 256 * m;
            if (e < NE) {
                a0[m] = ea[e*5+0]; a1[m] = ea[e*5+1]; a2[m] = ea[e*5+2];
                a3[m] = ea[e*5+3]; a4[m] = ea[e*5+4];
            } else {
                a0[m] = a1[m] = a2[m] = a3[m] = a4[m] = 0.f;
            }
            acc[m] = b2[0];
        }
        // histogram atomics issued before the MLP loop; latency hides under it.
        int pos[4] = {0, 0, 0, 0};
        #pragma unroll
        for (int m = 0; m < 4; ++m) {
            int e = e0 + 256 * m;
            if (e < ET) {
                int d = (e < NE) ? ei_dst[e] : (e - NE);
                pos[m] = atomicAdd(&deg[d], 1);
            }
        }
        #pragma unroll 4
        for (int j = 0; j < 64; ++j) {
            const float4 lo = *(const float4*)&wt[j * 8];
            const float4 hi = *(const float4*)&wt[j * 8 + 4];
            #pragma unroll
            for (int m = 0; m < 4; ++m) {
                float hj = hi.y + a0[m]*lo.x + a1[m]*lo.y + a2[m]*lo.z + a3[m]*lo.w + a4[m]*hi.x;
                acc[m] += fmaxf(hj, 0.f) * hi.z;
            }
        }
        float vsum = 0.f;
        #pragma unroll
        for (int m = 0; m < 4; ++m) {
            int e = e0 + 256 * m;
            if (e < NE) {
                float val = 1.f / (1.f + __expf(-acc[m]));
                ewp[e] = make_int2(pos[m], __float_as_int(val));
                vsum += val;
            } else if (e < ET) {
                ewp[e] = make_int2(pos[m], 0);
            }
        }
        // wave reduce + 4-word LDS combine
        #pragma unroll
        for (int m = 1; m <= 32; m <<= 1) vsum += __shfl_xor(vsum, m);
        if ((t & 63) == 0) wsum[t >> 6] = vsum;
        __syncthreads();
        if (t == 0) atomicAdd(ew_sum, (wsum[0] + wsum[1]) + (wsum[2] + wsum[3]));
    }
}

// ---------------- scan phase A (+ fused prep: ce[l][h]) ----------------
__global__ void scan_blocks(const int* __restrict__ deg, int* __restrict__ row_ptr,
                            int* __restrict__ bsum,
                            const float* __restrict__ We, const float* __restrict__ att_e,
                            float* __restrict__ ce) {
    __shared__ int sdata[SCAN_B];
    int t = threadIdx.x;
    int i = blockIdx.x * SCAN_B + t;
    if (i < 12) {
        int l = i >> 2, h = i & 3;
        float s = 0.f;
        for (int c = 0; c < 64; ++c)
            s += We[l*256 + h*64 + c] * att_e[l*256 + h*64 + c];
        ce[i] = s;
    }
    int v = (i < NN) ? deg[i] : 0;
    sdata[t] = v;
    __syncthreads();
    for (int off = 1; off < SCAN_B; off <<= 1) {
        int tv = (t >= off) ? sdata[t - off] : 0;
        __syncthreads();
        sdata[t] += tv;
        __syncthreads();
    }
    if (i < NN) row_ptr[i + 1] = sdata[t];
    if (t == SCAN_B - 1) bsum[blockIdx.x] = sdata[t];
}

__global__ void scan_fixup(const int* __restrict__ bsum, int* __restrict__ row_ptr) {
    __shared__ int sboff[64];
    int t = threadIdx.x;   // 256
    if (t < 64) {
        int v = (t < NBLK) ? bsum[t] : 0;
        int inc = v;
        #pragma unroll
        for (int off = 1; off < 64; off <<= 1) {
            int n = __shfl_up(inc, off);
            if (t >= off) inc += n;
        }
        sboff[t] = inc - v;   // exclusive scan
    }
    __syncthreads();
    int i = blockIdx.x * 256 + t;
    if (i < NN) row_ptr[i + 1] += sboff[i >> 10];
    if (i == 0) row_ptr[0] = 0;
}

// atomic-free scatter: slot = row_ptr[d] + pos from packed ewp.
__global__ void scatter_kernel(const int* __restrict__ ei_src, const int* __restrict__ ei_dst,
                               const int* __restrict__ row_ptr, const int2* __restrict__ ewp,
                               const float* __restrict__ ew_sum, int2* __restrict__ csr) {
    int e = blockIdx.x * 256 + threadIdx.x;
    if (e >= ET) return;
    int2 pw = ewp[e];
    int d, s, wbits;
    if (e < NE) {
        d = ei_dst[e];
        s = ei_src[e];
        wbits = pw.y;
    } else {
        d = s = e - NE;
        wbits = __float_as_int(ew_sum[0] * (1.f / (float)NE));
    }
    csr[row_ptr[d] + pw.x] = make_int2(s, wbits);
}

// ---------------- kernel: standalone transform (fallback path only) ----------------
__global__ void node_transform64(const float* __restrict__ xin, const float* __restrict__ W,
                                 const float* __restrict__ a_s, const float* __restrict__ a_d,
                                 unsigned short* __restrict__ hb, float* __restrict__ asrc,
                                 float* __restrict__ adst) {
    const int FIN = 64;
    const int t = threadIdx.x;
    const int n0 = blockIdx.x * NPB_T;
    __shared__ unsigned short hs[NPB_T * 256];
    float acc[NPB_T];
    #pragma unroll
    for (int i = 0; i < NPB_T; ++i) acc[i] = 0.f;
    #pragma unroll 4
    for (int k = 0; k < FIN; ++k) {
        float wv = W[k * 256 + t];
        #pragma unroll
        for (int i = 0; i < NPB_T; ++i)
            acc[i] += xin[(size_t)(n0 + i) * FIN + k] * wv;   // uniform address
    }
    int lane = t & 63, head = t >> 6;
    #pragma unroll
    for (int i = 0; i < NPB_T; ++i) hs[i * 256 + t] = f2bf(acc[i]);
    alpha_reduce_store<NPB_T>(acc, a_s[t], a_d[t], lane, head, n0, asrc, adst);
    __syncthreads();
    ((uint4*)(hb + (size_t)n0 * 256))[t] = ((const uint4*)hs)[t];
}

// ---------------- kernel: plain aggregation (layer 2 / fallback) ----------------
__global__ void gat_aggregate(const unsigned short* __restrict__ hb,
                              const float* __restrict__ asrc, const float* __restrict__ adst,
                              const int2* __restrict__ csr, const float* __restrict__ ce_l,
                              const float* __restrict__ bias_l,
                              const int* __restrict__ row_ptr,
                              float* __restrict__ xi, int residual) {
    int widx = (blockIdx.x * 256 + threadIdx.x) >> 6;   // node
    if (widx >= NN) return;
    int lane = threadIdx.x & 63;
    aggregate_one_node<false>(widx, lane, hb, asrc, adst, csr, ce_l, bias_l,
                              row_ptr, xi, residual, nullptr);
}

// ---------------- fused kernel: aggregate(layer l) + transform(layer l+1) ----------------
// 512 threads: waves 0-7 each aggregate one node (8 nodes/block); the elu'd xi rows
// are handed to the transform through LDS (bit-identical values); threads 0-255 then
// run the R12-proven transform body for the block's 8 nodes. Reads {hb_r, as_r, ad_r},
// writes {hb_w, as_w, ad_w} (double-buffered across layers to avoid the gather race).
__global__ __launch_bounds__(512)
void gat_agg_ff(const unsigned short* __restrict__ hb_r,
                const float* __restrict__ as_r, const float* __restrict__ ad_r,
                const int2* __restrict__ csr, const float* __restrict__ ce_l,
                const float* __restrict__ bias_l, const int* __restrict__ row_ptr,
                float* __restrict__ xi, int residual,
                const float* __restrict__ Wn, const float* __restrict__ a_s_n,
                const float* __restrict__ a_d_n,
                unsigned short* __restrict__ hb_w, float* __restrict__ as_w,
                float* __restrict__ ad_w) {
    __shared__ float xs[NPB_T * 64];           // 2 KB: xi rows for the transform
    __shared__ unsigned short hs[NPB_T * 256]; // 4 KB: bf16 bounce for coalesced hb store
    const int t = threadIdx.x;
    const int lane = t & 63;
    const int wid = t >> 6;                    // 0..7
    const int n0 = blockIdx.x * NPB_T;

    // ---- phase 1: aggregate (8 waves, 1 node each) ----
    aggregate_one_node<true>(n0 + wid, lane, hb_r, as_r, ad_r, csr, ce_l, bias_l,
                             row_ptr, xi, residual, &xs[wid * 64]);
    __syncthreads();

    // ---- phase 2: transform for next layer (threads 0-255, R12 structure) ----
    if (t < 256) {
        float acc[NPB_T];
        #pragma unroll
        for (int i = 0; i < NPB_T; ++i) acc[i] = 0.f;
        #pragma unroll 4
        for (int k = 0; k < 64; ++k) {
            float wv = Wn[k * 256 + t];
            #pragma unroll
            for (int i = 0; i < NPB_T; ++i)
                acc[i] += xs[i * 64 + k] * wv;   // uniform LDS broadcast
        }
        int head = t >> 6;
        #pragma unroll
        for (int i = 0; i < NPB_T; ++i) hs[i * 256 + t] = f2bf(acc[i]);
        alpha_reduce_store<NPB_T>(acc, a_s_n[t], a_d_n[t], lane, head, n0, as_w, ad_w);
    }
    __syncthreads();
    if (t < 256) ((uint4*)(hb_w + (size_t)n0 * 256))[t] = ((const uint4*)hs)[t];
}

// ---------------- kernel: LN + 2-layer MLP on the 50 target nodes ----------------
__global__ void readout_kernel(const float* __restrict__ xi, const int* __restrict__ batch,
                               const float* __restrict__ ln_g, const float* __restrict__ ln_b,
                               const float* __restrict__ l1w, const float* __restrict__ l1b,
                               const float* __restrict__ l2w, const float* __restrict__ l2b,
                               float* __restrict__ out) {
    int b = blockIdx.x;
    int t = threadIdx.x;   // 64 threads, one wave
    __shared__ int tg_s;
    if (t == 0) {
        int lo = 0, hi = NN;
        while (lo < hi) {
            int mid = (lo + hi) >> 1;
            if (batch[mid] < b) lo = mid + 1; else hi = mid;
        }
        tg_s = lo;
    }
    __syncthreads();
    int tg = tg_s;
    float x = xi[(size_t)tg * 64 + t];
    float s = x;
    #pragma unroll
    for (int mask = 1; mask <= 32; mask <<= 1) s += __shfl_xor(s, mask);
    float mu = s * (1.f / 64.f);
    float d = x - mu;
    float v = d * d;
    #pragma unroll
    for (int mask = 1; mask <= 32; mask <<= 1) v += __shfl_xor(v, mask);
    float var = v * (1.f / 64.f);
    float xn = d * rsqrtf(var + 1e-5f) * ln_g[t] + ln_b[t];
    __shared__ float sx[64];
    sx[t] = xn;
    __syncthreads();
    float acc = l1b[t];
    for (int k = 0; k < 64; ++k) acc += sx[k] * l1w[k * 64 + t];
    acc = eluf(acc);
    __shared__ float st[64];
    st[t] = acc;
    __syncthreads();
    if (t < 3) {
        float o = l2b[t];
        for (int k = 0; k < 64; ++k) o += st[k] * l2w[k * 3 + t];
        out[b * 3 + t] = o;
    }
}

extern "C" void kernel_launch(void* const* d_in, const int* in_sizes, int n_in,
                              void* d_out, int out_size, void* d_ws, size_t ws_size,
                              hipStream_t stream) {
    const float* x        = (const float*)d_in[0];
    const int*   ei       = (const int*)d_in[1];
    const float* ea       = (const float*)d_in[2];
    const int*   batch    = (const int*)d_in[3];
    const float* ee_w1    = (const float*)d_in[4];
    const float* ee_b1    = (const float*)d_in[5];
    const float* ee_w2    = (const float*)d_in[6];
    const float* ee_b2    = (const float*)d_in[7];
    const float* W1       = (const float*)d_in[8];
    const float* Ws       = (const float*)d_in[9];
    const float* att_src  = (const float*)d_in[10];
    const float* att_dst  = (const float*)d_in[11];
    const float* We       = (const float*)d_in[12];
    const float* att_e    = (const float*)d_in[13];
    const float* bias     = (const float*)d_in[14];
    const float* ln_g     = (const float*)d_in[15];
    const float* ln_b     = (const float*)d_in[16];
    const float* lin1_w   = (const float*)d_in[17];
    const float* lin1_b   = (const float*)d_in[18];
    const float* lin2_w   = (const float*)d_in[19];
    const float* lin2_b   = (const float*)d_in[20];
    float* out = (float*)d_out;

    // ---- workspace carve-up (256B aligned); optional double buffers LAST ----
    char* ws = (char*)d_ws;
    size_t off = 0;
    auto alloc = [&](size_t bytes) -> char* {
        char* p = ws + off;
        off += (bytes + 255) & ~(size_t)255;
        return p;
    };
    int2*  ewp     = (int2*)alloc((size_t)ET * 8);
    float* ce      = (float*)alloc(12 * 4);
    unsigned short* hbuf0 = (unsigned short*)alloc((size_t)NN * 256 * 2);
    float* as0     = (float*)alloc((size_t)NN * 4 * 4);
    float* ad0     = (float*)alloc((size_t)NN * 4 * 4);
    float* xi      = (float*)alloc((size_t)NN * 64 * 4);
    int*   deg     = (int*)alloc(((size_t)NN + 64) * 4); // deg | ew_sum
    float* ew_sum  = (float*)(deg + NN);
    int*   row_ptr = (int*)alloc((size_t)(NN + 1) * 4);
    int*   bsum    = (int*)alloc(64 * 4);
    int2*  csr     = (int2*)alloc((size_t)ET * 8);
    // double buffers for the fused path
    unsigned short* hbuf1 = (unsigned short*)alloc((size_t)NN * 256 * 2);
    float* as1     = (float*)alloc((size_t)NN * 4 * 4);
    float* ad1     = (float*)alloc((size_t)NN * 4 * 4);
    const bool fused = (off <= ws_size);
    (void)n_in; (void)in_sizes; (void)out_size;

    const int* ei_src = ei;
    const int* ei_dst = ei + NE;

    // 1. fused front: edge-MLP/histogram first, then node_transform<16>
    hipMemsetAsync(deg, 0, ((size_t)NN + 64) * 4, stream);
    front_kernel<<<NTB_F + MLPB, 256, 0, stream>>>(x, W1, att_src + 0 * 256, att_dst + 0 * 256,
                                                   hbuf0, as0, ad0,
                                                   ea, ee_w1, ee_b1, ee_w2, ee_b2,
                                                   ei_dst, deg, ewp, ew_sum);

    // 2. CSR by dst
    scan_blocks<<<NBLK, SCAN_B, 0, stream>>>(deg, row_ptr, bsum, We, att_e, ce);
    scan_fixup<<<(NN + 255) / 256, 256, 0, stream>>>(bsum, row_ptr);
    scatter_kernel<<<(ET + 255) / 256, 256, 0, stream>>>(ei_src, ei_dst, row_ptr, ewp, ew_sum, csr);

    // 3. three GAT layers
    const int agBlocks = (NN + 3) / 4;
    if (fused) {
        gat_agg_ff<<<NN / NPB_T, 512, 0, stream>>>(hbuf0, as0, ad0, csr, ce + 0 * 4,
                                                   bias + 0 * 64, row_ptr, xi, 0,
                                                   Ws + 0 * 64 * 256, att_src + 1 * 256,
                                                   att_dst + 1 * 256, hbuf1, as1, ad1);
        gat_agg_ff<<<NN / NPB_T, 512, 0, stream>>>(hbuf1, as1, ad1, csr, ce + 1 * 4,
                                                   bias + 1 * 64, row_ptr, xi, 1,
                                                   Ws + 1 * 64 * 256, att_src + 2 * 256,
                                                   att_dst + 2 * 256, hbuf0, as0, ad0);
        gat_aggregate<<<agBlocks, 256, 0, stream>>>(hbuf0, as0, ad0, csr, ce + 2 * 4,
                                                    bias + 2 * 64, row_ptr, xi, 1);
    } else {
        gat_aggregate<<<agBlocks, 256, 0, stream>>>(hbuf0, as0, ad0, csr, ce + 0 * 4,
                                                    bias + 0 * 64, row_ptr, xi, 0);
        for (int l = 0; l < 2; ++l) {
            node_transform64<<<NTB_T, 256, 0, stream>>>(xi, Ws + (size_t)l * 64 * 256,
                                                        att_src + (l + 1) * 256,
                                                        att_dst + (l + 1) * 256,
                                                        hbuf0, as0, ad0);
            gat_aggregate<<<agBlocks, 256, 0, stream>>>(hbuf0, as0, ad0, csr, ce + (l + 1) * 4,
                                                        bias + (l + 1) * 64, row_ptr, xi, 1);
        }
    }

    // 4. readout
    readout_kernel<<<NB, 64, 0, stream>>>(xi, batch, ln_g, ln_b, lin1_w, lin1_b, lin2_w, lin2_b, out);
}

// Round 7
// 301.585 us; speedup vs baseline: 1.6347x; 1.6347x over previous
//
#include <hip/hip_runtime.h>
#include <cstddef>
#include <cstdint>

constexpr int NN = 50000;          // nodes
constexpr int NE = 800000;         // edges (no self loops)
constexpr int ET = NE + NN;        // edges + self loops
constexpr int NB = 50;             // graphs
constexpr int SCAN_B = 1024;
constexpr int NBLK = (NN + SCAN_B - 1) / SCAN_B;   // 49
constexpr int NPB_F = 16;                          // nodes/block, front node branch
constexpr int NPB_T = 8;                           // nodes/block, transform (R12-proven)
constexpr int NTB_F = NN / NPB_F;                  // front node blocks (3125)
constexpr int MLPB = (ET + 1023) / 1024;           // edge-mlp blocks (4 edges/thread)

typedef float v2f __attribute__((ext_vector_type(2)));

__device__ __forceinline__ float eluf(float x) { return x > 0.f ? x : expm1f(x); }

// round-to-nearest-even fp32 -> bf16 (as ushort)
__device__ __forceinline__ unsigned short f2bf(float f) {
    unsigned int u = __float_as_uint(f);
    unsigned int r = (u + 0x7fffu + ((u >> 16) & 1u)) >> 16;
    return (unsigned short)r;
}

// Interleaved 4-node {vs,vd} reduction over 64 lanes (R14-proven).
// Node index for the store comes from nodeOf(g + (lane>>1)).
template <int NPB, typename NodeOf>
__device__ __forceinline__ void alpha_reduce_store(const float* acc, float as_t, float ad_t,
                                                   int lane, int head, NodeOf nodeOf,
                                                   float* __restrict__ asrc,
                                                   float* __restrict__ adst) {
    #pragma unroll
    for (int g = 0; g < NPB; g += 4) {
        float x0, x1, x2, x3;
        {
            float vs, vd;
            vs = acc[g + 0] * as_t; vd = acc[g + 0] * ad_t;
            x0 = ((lane & 1) ? vd : vs) + __shfl_xor((lane & 1) ? vs : vd, 1);
            vs = acc[g + 1] * as_t; vd = acc[g + 1] * ad_t;
            x1 = ((lane & 1) ? vd : vs) + __shfl_xor((lane & 1) ? vs : vd, 1);
            vs = acc[g + 2] * as_t; vd = acc[g + 2] * ad_t;
            x2 = ((lane & 1) ? vd : vs) + __shfl_xor((lane & 1) ? vs : vd, 1);
            vs = acc[g + 3] * as_t; vd = acc[g + 3] * ad_t;
            x3 = ((lane & 1) ? vd : vs) + __shfl_xor((lane & 1) ? vs : vd, 1);
        }
        float y0 = ((lane & 2) ? x1 : x0) + __shfl_xor((lane & 2) ? x0 : x1, 2);
        float y1 = ((lane & 2) ? x3 : x2) + __shfl_xor((lane & 2) ? x2 : x3, 2);
        float z  = ((lane & 4) ? y1 : y0) + __shfl_xor((lane & 4) ? y0 : y1, 4);
        z += __shfl_xor(z, 8);
        z += __shfl_xor(z, 16);
        z += __shfl_xor(z, 32);
        if (lane < 8) {
            int node = nodeOf(g + (lane >> 1));
            if (lane & 1) adst[node * 4 + head] = z;
            else          asrc[node * 4 + head] = z;
        }
    }
}

// ---------------- per-node aggregation body (R9 2-deep two-half structure) ----------------
__device__ __forceinline__ void aggregate_one_node(
        int widx, int lane,
        const unsigned short* __restrict__ hb,
        const float* __restrict__ asrc, const float* __restrict__ adst,
        const int2* __restrict__ csr, const float* __restrict__ ce_l,
        const float* __restrict__ bias_l, const int* __restrict__ row_ptr,
        float* __restrict__ xi, int residual) {
    int half = lane >> 5;
    int li = lane & 31;        // channels li*8 .. li*8+7
    int head = li >> 3;        // head
    int start = row_ptr[widx], end = row_ptr[widx + 1];
    float adw = adst[widx * 4 + head];
    float ceh = ce_l[head];
    const uint4* hbv = (const uint4*)hb;

    v2f acc2[4];
    #pragma unroll
    for (int r = 0; r < 4; ++r) { acc2[r].x = 0.f; acc2[r].y = 0.f; }
    float psum = 0.f;

    #define PROC(EI)                                                                  \
        {                                                                             \
            const int2 se = csr[EI];                                                  \
            int s = se.x;                                                             \
            float w = __int_as_float(se.y);                                           \
            const uint4 q = hbv[(unsigned)s * 32u + (unsigned)li];                    \
            float v = asrc[s * 4 + head] + adw + w * ceh;                             \
            v = v > 0.f ? v : 0.2f * v;                                               \
            float p = __expf(v);                                                      \
            psum += p;                                                                \
            v2f pv; pv.x = p; pv.y = p;                                               \
            v2f h0; h0.x = __uint_as_float(q.x << 16); h0.y = __uint_as_float(q.x & 0xffff0000u); \
            v2f h1; h1.x = __uint_as_float(q.y << 16); h1.y = __uint_as_float(q.y & 0xffff0000u); \
            v2f h2; h2.x = __uint_as_float(q.z << 16); h2.y = __uint_as_float(q.z & 0xffff0000u); \
            v2f h3; h3.x = __uint_as_float(q.w << 16); h3.y = __uint_as_float(q.w & 0xffff0000u); \
            acc2[0] += pv * h0;                                                       \
            acc2[1] += pv * h1;                                                       \
            acc2[2] += pv * h2;                                                       \
            acc2[3] += pv * h3;                                                       \
        }

    int ei = start + half;
    for (; ei + 2 < end; ei += 4) {   // 2 edges per half per iter -> 2 gathers in flight
        PROC(ei);
        PROC(ei + 2);
    }
    if (ei < end) PROC(ei);
    #undef PROC

    float acc[8];
    acc[0] = acc2[0].x; acc[1] = acc2[0].y; acc[2] = acc2[1].x; acc[3] = acc2[1].y;
    acc[4] = acc2[2].x; acc[5] = acc2[2].y; acc[6] = acc2[3].x; acc[7] = acc2[3].y;

    psum += __shfl_xor(psum, 32);
    #pragma unroll
    for (int r = 0; r < 8; ++r) acc[r] += __shfl_xor(acc[r], 32);

    float inv = 1.f / (psum + 1e-16f);
    #pragma unroll
    for (int r = 0; r < 8; ++r) acc[r] *= inv;

    #pragma unroll
    for (int r = 0; r < 8; ++r) {
        acc[r] += __shfl_xor(acc[r], 8);
        acc[r] += __shfl_xor(acc[r], 16);
        acc[r] *= 0.25f;
    }

    if (lane < 8) {
        int c0 = lane * 8;
        const float4 b0 = *(const float4*)(bias_l + c0);
        const float4 b1 = *(const float4*)(bias_l + c0 + 4);
        float4 v0, v1;
        v0.x = acc[0] + b0.x; v0.y = acc[1] + b0.y; v0.z = acc[2] + b0.z; v0.w = acc[3] + b0.w;
        v1.x = acc[4] + b1.x; v1.y = acc[5] + b1.y; v1.z = acc[6] + b1.z; v1.w = acc[7] + b1.w;
        float* xo = xi + (size_t)widx * 64 + c0;
        if (residual) {
            const float4 p0 = *(const float4*)xo;
            const float4 p1 = *(const float4*)(xo + 4);
            v0.x += p0.x; v0.y += p0.y; v0.z += p0.z; v0.w += p0.w;
            v1.x += p1.x; v1.y += p1.y; v1.z += p1.z; v1.w += p1.w;
        }
        v0.x = eluf(v0.x); v0.y = eluf(v0.y); v0.z = eluf(v0.z); v0.w = eluf(v0.w);
        v1.x = eluf(v1.x); v1.y = eluf(v1.y); v1.z = eluf(v1.z); v1.w = eluf(v1.w);
        *(float4*)xo = v0;
        *(float4*)(xo + 4) = v1;
    }
}

// ---------------- front kernel (R16-proven): node_transform<16> + edge-MLP/hist ----------------
__global__ void front_kernel(const float* __restrict__ xin, const float* __restrict__ W,
                             const float* __restrict__ a_s, const float* __restrict__ a_d,
                             unsigned short* __restrict__ hb, float* __restrict__ asrc,
                             float* __restrict__ adst,
                             const float* __restrict__ ea,
                             const float* __restrict__ w1, const float* __restrict__ b1,
                             const float* __restrict__ w2, const float* __restrict__ b2,
                             const int* __restrict__ ei_dst, int* __restrict__ deg,
                             int2* __restrict__ ewp, float* __restrict__ ew_sum) {
    __shared__ float wt[64 * 8];
    __shared__ float wsum[4];
    __shared__ unsigned short hs[NPB_F * 256];
    const int t = threadIdx.x;
    if (blockIdx.x < NTB_F) {
        const int FIN = 16;
        const int n0 = blockIdx.x * NPB_F;
        float acc[NPB_F];
        #pragma unroll
        for (int i = 0; i < NPB_F; ++i) acc[i] = 0.f;
        #pragma unroll 4
        for (int k = 0; k < FIN; ++k) {
            float wv = W[k * 256 + t];
            #pragma unroll
            for (int i = 0; i < NPB_F; ++i)
                acc[i] += xin[(size_t)(n0 + i) * FIN + k] * wv;   // uniform address
        }
        int lane = t & 63, head = t >> 6;
        #pragma unroll
        for (int i = 0; i < NPB_F; ++i) hs[i * 256 + t] = f2bf(acc[i]);
        alpha_reduce_store<NPB_F>(acc, a_s[t], a_d[t], lane, head,
                                  [&](int i) { return n0 + i; }, asrc, adst);
        __syncthreads();
        ((uint4*)(hb + (size_t)n0 * 256))[t]       = ((const uint4*)hs)[t];
        ((uint4*)(hb + (size_t)n0 * 256))[t + 256] = ((const uint4*)hs)[t + 256];
    } else {
        if (t < 64) {
            #pragma unroll
            for (int i = 0; i < 5; ++i) wt[t * 8 + i] = w1[i * 64 + t];
            wt[t * 8 + 5] = b1[t];
            wt[t * 8 + 6] = w2[t];
            wt[t * 8 + 7] = 0.f;
        }
        __syncthreads();
        const int e0 = (blockIdx.x - NTB_F) * 1024 + t;
        float a0[4], a1[4], a2[4], a3[4], a4[4], acc[4];
        #pragma unroll
        for (int m = 0; m < 4; ++m) {
            int e = e0 + 256 * m;
            if (e < NE) {
                a0[m] = ea[e*5+0]; a1[m] = ea[e*5+1]; a2[m] = ea[e*5+2];
                a3[m] = ea[e*5+3]; a4[m] = ea[e*5+4];
            } else {
                a0[m] = a1[m] = a2[m] = a3[m] = a4[m] = 0.f;
            }
            acc[m] = b2[0];
        }
        int pos[4] = {0, 0, 0, 0};
        #pragma unroll
        for (int m = 0; m < 4; ++m) {
            int e = e0 + 256 * m;
            if (e < ET) {
                int d = (e < NE) ? ei_dst[e] : (e - NE);
                pos[m] = atomicAdd(&deg[d], 1);
            }
        }
        #pragma unroll 4
        for (int j = 0; j < 64; ++j) {
            const float4 lo = *(const float4*)&wt[j * 8];
            const float4 hi = *(const float4*)&wt[j * 8 + 4];
            #pragma unroll
            for (int m = 0; m < 4; ++m) {
                float hj = hi.y + a0[m]*lo.x + a1[m]*lo.y + a2[m]*lo.z + a3[m]*lo.w + a4[m]*hi.x;
                acc[m] += fmaxf(hj, 0.f) * hi.z;
            }
        }
        float vsum = 0.f;
        #pragma unroll
        for (int m = 0; m < 4; ++m) {
            int e = e0 + 256 * m;
            if (e < NE) {
                float val = 1.f / (1.f + __expf(-acc[m]));
                ewp[e] = make_int2(pos[m], __float_as_int(val));
                vsum += val;
            } else if (e < ET) {
                ewp[e] = make_int2(pos[m], 0);
            }
        }
        #pragma unroll
        for (int m = 1; m <= 32; m <<= 1) vsum += __shfl_xor(vsum, m);
        if ((t & 63) == 0) wsum[t >> 6] = vsum;
        __syncthreads();
        if (t == 0) atomicAdd(ew_sum, (wsum[0] + wsum[1]) + (wsum[2] + wsum[3]));
    }
}

// ---------------- scan phase A (+ fused prep: ce[l][h]) ----------------
__global__ void scan_blocks(const int* __restrict__ deg, int* __restrict__ row_ptr,
                            int* __restrict__ bsum,
                            const float* __restrict__ We, const float* __restrict__ att_e,
                            float* __restrict__ ce) {
    __shared__ int sdata[SCAN_B];
    int t = threadIdx.x;
    int i = blockIdx.x * SCAN_B + t;
    if (i < 12) {
        int l = i >> 2, h = i & 3;
        float s = 0.f;
        for (int c = 0; c < 64; ++c)
            s += We[l*256 + h*64 + c] * att_e[l*256 + h*64 + c];
        ce[i] = s;
    }
    int v = (i < NN) ? deg[i] : 0;
    sdata[t] = v;
    __syncthreads();
    for (int off = 1; off < SCAN_B; off <<= 1) {
        int tv = (t >= off) ? sdata[t - off] : 0;
        __syncthreads();
        sdata[t] += tv;
        __syncthreads();
    }
    if (i < NN) row_ptr[i + 1] = sdata[t];
    if (t == SCAN_B - 1) bsum[blockIdx.x] = sdata[t];
}

__global__ void scan_fixup(const int* __restrict__ bsum, int* __restrict__ row_ptr) {
    __shared__ int sboff[64];
    int t = threadIdx.x;   // 256
    if (t < 64) {
        int v = (t < NBLK) ? bsum[t] : 0;
        int inc = v;
        #pragma unroll
        for (int off = 1; off < 64; off <<= 1) {
            int n = __shfl_up(inc, off);
            if (t >= off) inc += n;
        }
        sboff[t] = inc - v;   // exclusive scan
    }
    __syncthreads();
    int i = blockIdx.x * 256 + t;
    if (i < NN) row_ptr[i + 1] += sboff[i >> 10];
    if (i == 0) row_ptr[0] = 0;
}

// atomic-free scatter: slot = row_ptr[d] + pos from packed ewp.
__global__ void scatter_kernel(const int* __restrict__ ei_src, const int* __restrict__ ei_dst,
                               const int* __restrict__ row_ptr, const int2* __restrict__ ewp,
                               const float* __restrict__ ew_sum, int2* __restrict__ csr) {
    int e = blockIdx.x * 256 + threadIdx.x;
    if (e >= ET) return;
    int2 pw = ewp[e];
    int d, s, wbits;
    if (e < NE) {
        d = ei_dst[e];
        s = ei_src[e];
        wbits = pw.y;
    } else {
        d = s = e - NE;
        wbits = __float_as_int(ew_sum[0] * (1.f / (float)NE));
    }
    csr[row_ptr[d] + pw.x] = make_int2(s, wbits);
}

// ---------------- R18 cone kernels: build S1 = in-nbrs(targets), S2 = in-nbrs(S1) ----
__global__ void mark1_kernel(const int* __restrict__ batch, const int* __restrict__ row_ptr,
                             const int2* __restrict__ csr, int* __restrict__ flag1,
                             int* __restrict__ list1, int* __restrict__ cnt1,
                             int* __restrict__ tgt) {
    int b = blockIdx.x;         // one block per graph
    int t = threadIdx.x;        // 64
    __shared__ int tg_s;
    if (t == 0) {
        int lo = 0, hi = NN;
        while (lo < hi) {
            int mid = (lo + hi) >> 1;
            if (batch[mid] < b) lo = mid + 1; else hi = mid;
        }
        tg_s = lo;
        tgt[b] = lo;
    }
    __syncthreads();
    int tg = tg_s;
    int start = row_ptr[tg], end = row_ptr[tg + 1];
    for (int j = start + t; j < end; j += 64) {
        int s = csr[j].x;       // self-loop guarantees tg itself is included
        if (atomicExch(&flag1[s], 1) == 0) {
            int p = atomicAdd(cnt1, 1);
            if (p < NN) list1[p] = s;
        }
    }
}

__global__ void mark2_kernel(const int* __restrict__ row_ptr, const int2* __restrict__ csr,
                             const int* __restrict__ list1, const int* __restrict__ cnt1,
                             int* __restrict__ flag2, int* __restrict__ list2,
                             int* __restrict__ cnt2) {
    int i = blockIdx.x * 256 + threadIdx.x;
    if (i >= cnt1[0] || i >= NN) return;
    int u = list1[i];
    int start = row_ptr[u], end = row_ptr[u + 1];
    for (int j = start; j < end; ++j) {
        int s = csr[j].x;       // self-loops make S1 subset of S2
        if (atomicExch(&flag2[s], 1) == 0) {
            int p = atomicAdd(cnt2, 1);
            if (p < NN) list2[p] = s;
        }
    }
}

// ---------------- list-restricted transform (h = xi @ W, FIN=64) ----------------
__global__ void transform64_list(const int* __restrict__ list, const int* __restrict__ cnt,
                                 const float* __restrict__ xin, const float* __restrict__ W,
                                 const float* __restrict__ a_s, const float* __restrict__ a_d,
                                 unsigned short* __restrict__ hb, float* __restrict__ asrc,
                                 float* __restrict__ adst) {
    const int t = threadIdx.x;
    const int n0 = blockIdx.x * NPB_T;
    const int nv = min(cnt[0], NN);
    if (n0 >= nv) return;
    __shared__ unsigned short hs[NPB_T * 256];
    __shared__ int nls[NPB_T];
    if (t < NPB_T) nls[t] = list[min(n0 + t, nv - 1)];  // clamp -> benign duplicates
    __syncthreads();
    int nreg[NPB_T];
    #pragma unroll
    for (int i = 0; i < NPB_T; ++i) nreg[i] = nls[i];
    float acc[NPB_T];
    #pragma unroll
    for (int i = 0; i < NPB_T; ++i) acc[i] = 0.f;
    #pragma unroll 4
    for (int k = 0; k < 64; ++k) {
        float wv = W[k * 256 + t];
        #pragma unroll
        for (int i = 0; i < NPB_T; ++i)
            acc[i] += xin[(size_t)nreg[i] * 64 + k] * wv;   // wave-uniform address
    }
    int lane = t & 63, head = t >> 6;
    #pragma unroll
    for (int i = 0; i < NPB_T; ++i) hs[i * 256 + t] = f2bf(acc[i]);
    alpha_reduce_store<NPB_T>(acc, a_s[t], a_d[t], lane, head,
                              [&](int i) { return nls[i]; }, asrc, adst);
    __syncthreads();
    // per-node scattered row store: thread t -> node t>>5, uint4 t&31
    int nn = nls[t >> 5];
    ((uint4*)(hb + (size_t)nn * 256))[t & 31] = ((const uint4*)hs)[t];
}

// ---------------- list-restricted aggregation ----------------
__global__ void gat_aggregate_list(const int* __restrict__ list, const int* __restrict__ cnt,
                                   int cnt_const,
                                   const unsigned short* __restrict__ hb,
                                   const float* __restrict__ asrc, const float* __restrict__ adst,
                                   const int2* __restrict__ csr, const float* __restrict__ ce_l,
                                   const float* __restrict__ bias_l,
                                   const int* __restrict__ row_ptr,
                                   float* __restrict__ xi, int residual) {
    int idx = (blockIdx.x * 256 + threadIdx.x) >> 6;
    int n = cnt ? min(cnt[0], NN) : cnt_const;
    if (idx >= n) return;
    int widx = list[idx];
    int lane = threadIdx.x & 63;
    aggregate_one_node(widx, lane, hb, asrc, adst, csr, ce_l, bias_l, row_ptr, xi, residual);
}

// ---------------- kernel: LN + 2-layer MLP on the 50 target nodes ----------------
__global__ void readout_kernel(const float* __restrict__ xi, const int* __restrict__ tgt,
                               const float* __restrict__ ln_g, const float* __restrict__ ln_b,
                               const float* __restrict__ l1w, const float* __restrict__ l1b,
                               const float* __restrict__ l2w, const float* __restrict__ l2b,
                               float* __restrict__ out) {
    int b = blockIdx.x;
    int t = threadIdx.x;   // 64 threads, one wave
    int tg = tgt[b];
    float x = xi[(size_t)tg * 64 + t];
    float s = x;
    #pragma unroll
    for (int mask = 1; mask <= 32; mask <<= 1) s += __shfl_xor(s, mask);
    float mu = s * (1.f / 64.f);
    float d = x - mu;
    float v = d * d;
    #pragma unroll
    for (int mask = 1; mask <= 32; mask <<= 1) v += __shfl_xor(v, mask);
    float var = v * (1.f / 64.f);
    float xn = d * rsqrtf(var + 1e-5f) * ln_g[t] + ln_b[t];
    __shared__ float sx[64];
    sx[t] = xn;
    __syncthreads();
    float acc = l1b[t];
    for (int k = 0; k < 64; ++k) acc += sx[k] * l1w[k * 64 + t];
    acc = eluf(acc);
    __shared__ float st[64];
    st[t] = acc;
    __syncthreads();
    if (t < 3) {
        float o = l2b[t];
        for (int k = 0; k < 64; ++k) o += st[k] * l2w[k * 3 + t];
        out[b * 3 + t] = o;
    }
}

extern "C" void kernel_launch(void* const* d_in, const int* in_sizes, int n_in,
                              void* d_out, int out_size, void* d_ws, size_t ws_size,
                              hipStream_t stream) {
    const float* x        = (const float*)d_in[0];
    const int*   ei       = (const int*)d_in[1];
    const float* ea       = (const float*)d_in[2];
    const int*   batch    = (const int*)d_in[3];
    const float* ee_w1    = (const float*)d_in[4];
    const float* ee_b1    = (const float*)d_in[5];
    const float* ee_w2    = (const float*)d_in[6];
    const float* ee_b2    = (const float*)d_in[7];
    const float* W1       = (const float*)d_in[8];
    const float* Ws       = (const float*)d_in[9];
    const float* att_src  = (const float*)d_in[10];
    const float* att_dst  = (const float*)d_in[11];
    const float* We       = (const float*)d_in[12];
    const float* att_e    = (const float*)d_in[13];
    const float* bias     = (const float*)d_in[14];
    const float* ln_g     = (const float*)d_in[15];
    const float* ln_b     = (const float*)d_in[16];
    const float* lin1_w   = (const float*)d_in[17];
    const float* lin1_b   = (const float*)d_in[18];
    const float* lin2_w   = (const float*)d_in[19];
    const float* lin2_b   = (const float*)d_in[20];
    float* out = (float*)d_out;

    // ---- workspace carve-up (256B aligned) ----
    char* ws = (char*)d_ws;
    size_t off = 0;
    auto alloc = [&](size_t bytes) -> char* {
        char* p = ws + off;
        off += (bytes + 255) & ~(size_t)255;
        return p;
    };
    int2*  ewp     = (int2*)alloc((size_t)ET * 8);
    float* ce      = (float*)alloc(12 * 4);
    unsigned short* hbuf = (unsigned short*)alloc((size_t)NN * 256 * 2);
    float* asrc    = (float*)alloc((size_t)NN * 4 * 4);
    float* adst    = (float*)alloc((size_t)NN * 4 * 4);
    float* xi      = (float*)alloc((size_t)NN * 64 * 4);
    // zeroed region: deg | flag1 | flag2 | misc(ew_sum, cnt1, cnt2)
    int*   deg     = (int*)alloc(((size_t)NN * 3 + 64) * 4);
    int*   flag1   = deg + NN;
    int*   flag2   = deg + 2 * NN;
    float* ew_sum  = (float*)(deg + 3 * NN);
    int*   cnt1    = deg + 3 * NN + 1;
    int*   cnt2    = deg + 3 * NN + 2;
    int*   row_ptr = (int*)alloc((size_t)(NN + 1) * 4);
    int*   bsum    = (int*)alloc(64 * 4);
    int2*  csr     = (int2*)alloc((size_t)ET * 8);
    int*   list1   = (int*)alloc((size_t)NN * 4);
    int*   list2   = (int*)alloc((size_t)NN * 4);
    int*   tgt     = (int*)alloc(NB * 4);
    (void)ws_size; (void)n_in; (void)in_sizes; (void)out_size;

    const int* ei_src = ei;
    const int* ei_dst = ei + NE;

    // 1. fused front: node_transform<16> (layer-0, all nodes) + edge-MLP + histogram
    hipMemsetAsync(deg, 0, ((size_t)NN * 3 + 64) * 4, stream);
    front_kernel<<<NTB_F + MLPB, 256, 0, stream>>>(x, W1, att_src + 0 * 256, att_dst + 0 * 256,
                                                   hbuf, asrc, adst,
                                                   ea, ee_w1, ee_b1, ee_w2, ee_b2,
                                                   ei_dst, deg, ewp, ew_sum);

    // 2. CSR by dst
    scan_blocks<<<NBLK, SCAN_B, 0, stream>>>(deg, row_ptr, bsum, We, att_e, ce);
    scan_fixup<<<(NN + 255) / 256, 256, 0, stream>>>(bsum, row_ptr);
    scatter_kernel<<<(ET + 255) / 256, 256, 0, stream>>>(ei_src, ei_dst, row_ptr, ewp, ew_sum, csr);

    // 3. dependency cone: S1 = in-nbrs(targets) (~850), S2 = in-nbrs(S1) (~12.4k)
    mark1_kernel<<<NB, 64, 0, stream>>>(batch, row_ptr, csr, flag1, list1, cnt1, tgt);
    mark2_kernel<<<(NN + 255) / 256, 256, 0, stream>>>(row_ptr, csr, list1, cnt1,
                                                       flag2, list2, cnt2);

    // 4. three GAT layers restricted to the cone (identical arithmetic per node)
    gat_aggregate_list<<<(NN + 3) / 4, 256, 0, stream>>>(list2, cnt2, 0, hbuf, asrc, adst,
                                                         csr, ce + 0 * 4, bias + 0 * 64,
                                                         row_ptr, xi, 0);
    transform64_list<<<NN / NPB_T, 256, 0, stream>>>(list2, cnt2, xi, Ws + 0 * 64 * 256,
                                                     att_src + 1 * 256, att_dst + 1 * 256,
                                                     hbuf, asrc, adst);
    gat_aggregate_list<<<(NN + 3) / 4, 256, 0, stream>>>(list1, cnt1, 0, hbuf, asrc, adst,
                                                         csr, ce + 1 * 4, bias + 1 * 64,
                                                         row_ptr, xi, 1);
    transform64_list<<<NN / NPB_T, 256, 0, stream>>>(list1, cnt1, xi, Ws + 1 * 64 * 256,
                                                     att_src + 2 * 256, att_dst + 2 * 256,
                                                     hbuf, asrc, adst);
    gat_aggregate_list<<<(NB + 3) / 4, 256, 0, stream>>>(tgt, nullptr, NB, hbuf, asrc, adst,
                                                         csr, ce + 2 * 4, bias + 2 * 64,
                                                         row_ptr, xi, 1);

    // 5. readout (targets already computed by mark1)
    readout_kernel<<<NB, 64, 0, stream>>>(xi, tgt, ln_g, ln_b, lin1_w, lin1_b, lin2_w, lin2_b, out);
}